// Round 7
// baseline (89.982 us; speedup 1.0000x reference)
//
#include <hip/hip_runtime.h>

// YOLO loss: S=7, B=2, C=20, LAMBDA_COORD=5, LAMBDA_NOOBJ=0.5, N=8192.
// pred: (8192, 49*30) f32, target: (8192, 49*25) f32, out: scalar f32.
// M = 401408 cells = 3136 chunks of 128 (round-6 kernel-1 body).
// Single dispatch: each block publishes its partial with a write-through
// agent-scope store, orders with one s_waitcnt vmcnt(0), then one relaxed
// agent-scope ticket fetch_add. The block whose ticket hits residue
// NCHUNKS-1 is the LAST publisher (release sequence over the RMW chain);
// it reads all partials (agent-scope loads bypass stale local L2), does a
// fixed-order sum, writes out, resets the ticket. No spinning -> no
// per-poll L2 invalidates (round-5 lesson). Heal-CAS at block start maps
// any ticket >= NCHUNKS (incl. 0xAA poison) to 0 -> exactly one winner
// for any initial workspace state.

#define NBATCH  8192
#define PSTRIDE 30
#define TSTRIDE 25
#define TPB     128
#define NCHUNKS 3136       // M / TPB

__global__ __launch_bounds__(TPB) void yolo_onepass_kernel(
    const float* __restrict__ pred,
    const float* __restrict__ tgt,
    float* __restrict__ out,
    float* __restrict__ partials,
    unsigned int* __restrict__ ticket,
    float invN)
{
    __shared__ float sp[TPB * PSTRIDE];   // 15360 B
    __shared__ float st[TPB * TSTRIDE];   // 12800 B
    __shared__ float ws[2];
    __shared__ int   winflag;

    const int tid = threadIdx.x;

    // ---- heal ticket if it holds poison/garbage (>= NCHUNKS) ----
    if (tid == 0) {
        unsigned int v = __hip_atomic_load(ticket, __ATOMIC_RELAXED,
                                           __HIP_MEMORY_SCOPE_AGENT);
        if (v >= NCHUNKS) {
            unsigned int expd = v, zero = 0u;
            __hip_atomic_compare_exchange_strong(
                ticket, &expd, zero,
                __ATOMIC_RELAXED, __ATOMIC_RELAXED, __HIP_MEMORY_SCOPE_AGENT);
        }
    }

    const size_t c0 = (size_t)blockIdx.x * TPB;

    // ---- stage pred chunk: 960 float4, coalesced & 16B-aligned ----
    const float4* gp = (const float4*)(pred + c0 * PSTRIDE);
    float4* lp = (float4*)sp;
    #pragma unroll
    for (int k = 0; k < 7; ++k)
        lp[tid + k * TPB] = gp[tid + k * TPB];
    if (tid < 64)
        lp[tid + 7 * TPB] = gp[tid + 7 * TPB];

    // ---- stage target chunk: 800 float4 ----
    const float4* gt = (const float4*)(tgt + c0 * TSTRIDE);
    float4* lt = (float4*)st;
    #pragma unroll
    for (int k = 0; k < 6; ++k)
        lt[tid + k * TPB] = gt[tid + k * TPB];
    if (tid < 32)
        lt[tid + 6 * TPB] = gt[tid + 6 * TPB];

    __syncthreads();

    // ---- per-cell compute from LDS ----
    const float* p = sp + tid * PSTRIDE;
    const float* t = st + tid * TSTRIDE;

    int cell = (int)((c0 + tid) % 49);
    float gy = (float)(cell / 7);
    float gx = (float)(cell % 7);
    const float invS = 1.0f / 7.0f;

    float t0 = t[0], tx = t[1], ty = t[2], tw = t[3], th = t[4];
    float objf   = (t0 == 1.0f) ? 1.0f : 0.0f;
    float noobjf = (t0 == 0.0f) ? 1.0f : 0.0f;

    float tcx = (gx + tx) * invS, tcy = (gy + ty) * invS;
    float tx1 = tcx - tw * 0.5f, ty1 = tcy - th * 0.5f;
    float tx2 = tcx + tw * 0.5f, ty2 = tcy + th * 0.5f;
    float area_t = (tx2 - tx1) * (ty2 - ty1);

    float conf[2], bx[2], by[2], bw[2], bh[2], iou[2];
    #pragma unroll
    for (int b = 0; b < 2; ++b) {
        conf[b] = p[b * 5 + 0];
        bx[b]   = p[b * 5 + 1];
        by[b]   = p[b * 5 + 2];
        bw[b]   = p[b * 5 + 3];
        bh[b]   = p[b * 5 + 4];
        float ax = fabsf(bx[b]), ay = fabsf(by[b]);
        float aw = fabsf(bw[b]), ah = fabsf(bh[b]);
        float cx = (gx + ax) * invS, cy = (gy + ay) * invS;
        float x1 = cx - aw * 0.5f, y1 = cy - ah * 0.5f;
        float x2 = cx + aw * 0.5f, y2 = cy + ah * 0.5f;
        float ltx = fmaxf(x1, tx1), lty = fmaxf(y1, ty1);
        float rbx = fminf(x2, tx2), rby = fminf(y2, ty2);
        float wx = fmaxf(rbx - ltx, 0.0f);
        float wy = fmaxf(rby - lty, 0.0f);
        float inter = wx * wy;
        float area_p = (x2 - x1) * (y2 - y1);
        iou[b] = inter / (area_p + area_t - inter);
    }

    int best = (iou[1] > iou[0]) ? 1 : 0;       // first index wins ties
    float miou = fmaxf(iou[0], iou[1]);

    float rc = conf[best];
    float rx = bx[best], ry = by[best], rw = bw[best], rh = bh[best];

    float dx = rx - tx, dy = ry - ty;
    float sw = sqrtf(fabsf(rw)) - sqrtf(fabsf(tw));
    float sh = sqrtf(fabsf(rh)) - sqrtf(fabsf(th));
    float loc = dx * dx + dy * dy + sw * sw + sh * sh;

    float oc = rc - miou;
    oc = oc * oc;

    float no = conf[0] * conf[0] + conf[1] * conf[1];

    float cls = 0.0f;
    #pragma unroll
    for (int k = 0; k < 20; ++k) {
        float d = p[10 + k] - t[5 + k];
        cls += d * d;
    }

    float part = objf * (5.0f * loc + oc + cls) + 0.5f * noobjf * no;

    // ---- block reduce (2 waves) ----
    #pragma unroll
    for (int off = 32; off > 0; off >>= 1)
        part += __shfl_down(part, off, 64);
    int lane = tid & 63, wid = tid >> 6;
    if (lane == 0) ws[wid] = part;
    __syncthreads();

    // ---- publish partial (write-through), then ticket ----
    if (tid == 0) {
        float bsum = ws[0] + ws[1];
        __hip_atomic_store(&partials[blockIdx.x], bsum,
                           __ATOMIC_RELAXED, __HIP_MEMORY_SCOPE_AGENT);
        // order: partial must reach coherence point before ticket add
        asm volatile("s_waitcnt vmcnt(0)" ::: "memory");
        unsigned int old = __hip_atomic_fetch_add(
            ticket, 1u, __ATOMIC_RELAXED, __HIP_MEMORY_SCOPE_AGENT);
        winflag = (old % NCHUNKS == NCHUNKS - 1) ? 1 : 0;
    }
    __syncthreads();

    // ---- last publisher does the fixed-order final sum ----
    if (winflag) {
        float s = 0.0f;
        for (int i = tid; i < NCHUNKS; i += TPB)
            s += __hip_atomic_load(&partials[i], __ATOMIC_RELAXED,
                                   __HIP_MEMORY_SCOPE_AGENT);
        #pragma unroll
        for (int off = 32; off > 0; off >>= 1)
            s += __shfl_down(s, off, 64);
        if (lane == 0) ws[wid] = s;
        __syncthreads();
        if (tid == 0) {
            __hip_atomic_store(out, (ws[0] + ws[1]) * invN,
                               __ATOMIC_RELAXED, __HIP_MEMORY_SCOPE_AGENT);
            __hip_atomic_store(ticket, 0u,
                               __ATOMIC_RELAXED, __HIP_MEMORY_SCOPE_AGENT);
        }
    }
}

extern "C" void kernel_launch(void* const* d_in, const int* in_sizes, int n_in,
                              void* d_out, int out_size, void* d_ws, size_t ws_size,
                              hipStream_t stream) {
    const float* pred = (const float*)d_in[0];
    const float* tgt  = (const float*)d_in[1];
    float* out = (float*)d_out;

    // d_ws layout: [0, 12544)   partials (3136 f32)
    //              [16384]      ticket (u32, self-healing)
    float* partials     = (float*)d_ws;
    unsigned int* ticket = (unsigned int*)((char*)d_ws + 16384);

    yolo_onepass_kernel<<<NCHUNKS, TPB, 0, stream>>>(
        pred, tgt, out, partials, ticket, 1.0f / (float)NBATCH);
}

// Round 8
// 27.220 us; speedup vs baseline: 3.3058x; 3.3058x over previous
//
#include <hip/hip_runtime.h>

// YOLO loss: S=7, B=2, C=20, LAMBDA_COORD=5, LAMBDA_NOOBJ=0.5, N=8192.
// pred: (8192, 49*30) f32, target: (8192, 49*25) f32, out: scalar f32.
// M = 401408 cells = 6272 chunks of 64. One WAVE per block: staging and
// compute are wave-local, so NO __syncthreads anywhere in kernel 1 —
// no vmcnt full-drain barrier stalls; 14.1 KiB LDS -> 11 blocks/CU of
// independent wave-streams. Two-dispatch structure (rounds 4/5/7 proved
// every intra-kernel cross-XCD handshake — grid.sync, spin-acquire,
// same-address ticket RMW — costs 2-4x more than the dispatch bubble).

#define NBATCH  8192
#define PSTRIDE 30
#define TSTRIDE 25
#define TPB     64
#define NCHUNKS 6272       // M / 64

__global__ __launch_bounds__(TPB) void yolo_partial_kernel(
    const float* __restrict__ pred,
    const float* __restrict__ tgt,
    float* __restrict__ partials)
{
    __shared__ float sp[TPB * PSTRIDE];   // 7680 B
    __shared__ float st[TPB * TSTRIDE];   // 6400 B

    const int lane = threadIdx.x;          // one wave: lane == tid
    const size_t c0 = (size_t)blockIdx.x * TPB;

    // ---- stage pred chunk: 480 float4, coalesced & 16B-aligned ----
    const float4* gp = (const float4*)(pred + c0 * PSTRIDE);
    float4* lp = (float4*)sp;
    #pragma unroll
    for (int k = 0; k < 7; ++k)
        lp[lane + k * TPB] = gp[lane + k * TPB];
    if (lane < 32)                         // 480 - 7*64
        lp[lane + 7 * TPB] = gp[lane + 7 * TPB];

    // ---- stage target chunk: 400 float4 ----
    const float4* gt = (const float4*)(tgt + c0 * TSTRIDE);
    float4* lt = (float4*)st;
    #pragma unroll
    for (int k = 0; k < 6; ++k)
        lt[lane + k * TPB] = gt[lane + k * TPB];
    if (lane < 16)                         // 400 - 6*64
        lt[lane + 6 * TPB] = gt[lane + 6 * TPB];

    // NO __syncthreads: same wave wrote and reads; the compiler's
    // s_waitcnt lgkmcnt ordering on aliasing LDS ops is sufficient.

    // ---- per-cell compute from LDS ----
    const float* p = sp + lane * PSTRIDE;
    const float* t = st + lane * TSTRIDE;

    int cell = (int)((c0 + lane) % 49);
    float gy = (float)(cell / 7);
    float gx = (float)(cell % 7);
    const float invS = 1.0f / 7.0f;

    float t0 = t[0], tx = t[1], ty = t[2], tw = t[3], th = t[4];
    float objf   = (t0 == 1.0f) ? 1.0f : 0.0f;
    float noobjf = (t0 == 0.0f) ? 1.0f : 0.0f;

    float tcx = (gx + tx) * invS, tcy = (gy + ty) * invS;
    float tx1 = tcx - tw * 0.5f, ty1 = tcy - th * 0.5f;
    float tx2 = tcx + tw * 0.5f, ty2 = tcy + th * 0.5f;
    float area_t = (tx2 - tx1) * (ty2 - ty1);

    float conf[2], bx[2], by[2], bw[2], bh[2], iou[2];
    #pragma unroll
    for (int b = 0; b < 2; ++b) {
        conf[b] = p[b * 5 + 0];
        bx[b]   = p[b * 5 + 1];
        by[b]   = p[b * 5 + 2];
        bw[b]   = p[b * 5 + 3];
        bh[b]   = p[b * 5 + 4];
        float ax = fabsf(bx[b]), ay = fabsf(by[b]);
        float aw = fabsf(bw[b]), ah = fabsf(bh[b]);
        float cx = (gx + ax) * invS, cy = (gy + ay) * invS;
        float x1 = cx - aw * 0.5f, y1 = cy - ah * 0.5f;
        float x2 = cx + aw * 0.5f, y2 = cy + ah * 0.5f;
        float ltx = fmaxf(x1, tx1), lty = fmaxf(y1, ty1);
        float rbx = fminf(x2, tx2), rby = fminf(y2, ty2);
        float wx = fmaxf(rbx - ltx, 0.0f);
        float wy = fmaxf(rby - lty, 0.0f);
        float inter = wx * wy;
        float area_p = (x2 - x1) * (y2 - y1);
        iou[b] = inter / (area_p + area_t - inter);
    }

    int best = (iou[1] > iou[0]) ? 1 : 0;       // first index wins ties
    float miou = fmaxf(iou[0], iou[1]);

    float rc = conf[best];
    float rx = bx[best], ry = by[best], rw = bw[best], rh = bh[best];

    float dx = rx - tx, dy = ry - ty;
    float sw = sqrtf(fabsf(rw)) - sqrtf(fabsf(tw));
    float sh = sqrtf(fabsf(rh)) - sqrtf(fabsf(th));
    float loc = dx * dx + dy * dy + sw * sw + sh * sh;

    float oc = rc - miou;
    oc = oc * oc;

    float no = conf[0] * conf[0] + conf[1] * conf[1];

    float cls = 0.0f;
    #pragma unroll
    for (int k = 0; k < 20; ++k) {
        float d = p[10 + k] - t[5 + k];
        cls += d * d;
    }

    float part = objf * (5.0f * loc + oc + cls) + 0.5f * noobjf * no;

    // ---- wave reduce, one plain store per block ----
    #pragma unroll
    for (int off = 32; off > 0; off >>= 1)
        part += __shfl_down(part, off, 64);
    if (lane == 0)
        partials[blockIdx.x] = part;
}

__global__ __launch_bounds__(256) void yolo_final_kernel(
    const float* __restrict__ partials,
    float* __restrict__ out, float invN)
{
    const int tid = threadIdx.x;
    float s = 0.0f;
    for (int i = tid; i < NCHUNKS; i += 256)
        s += partials[i];
    #pragma unroll
    for (int off = 32; off > 0; off >>= 1)
        s += __shfl_down(s, off, 64);
    __shared__ float ws[4];
    int lane = tid & 63, wid = tid >> 6;
    if (lane == 0) ws[wid] = s;
    __syncthreads();
    if (tid == 0)
        out[0] = (ws[0] + ws[1] + ws[2] + ws[3]) * invN;
}

extern "C" void kernel_launch(void* const* d_in, const int* in_sizes, int n_in,
                              void* d_out, int out_size, void* d_ws, size_t ws_size,
                              hipStream_t stream) {
    const float* pred = (const float*)d_in[0];
    const float* tgt  = (const float*)d_in[1];
    float* out = (float*)d_out;
    float* partials = (float*)d_ws;        // 6272 f32, fully overwritten

    yolo_partial_kernel<<<NCHUNKS, TPB, 0, stream>>>(pred, tgt, partials);
    yolo_final_kernel<<<1, 256, 0, stream>>>(partials, out, 1.0f / (float)NBATCH);
}

// Round 9
// 23.238 us; speedup vs baseline: 3.8723x; 1.1714x over previous
//
#include <hip/hip_runtime.h>

// YOLO loss: S=7, B=2, C=20, LAMBDA_COORD=5, LAMBDA_NOOBJ=0.5, N=8192.
// pred: (8192, 49*30) f32, target: (8192, 49*25) f32, out: scalar f32.
// M = 401408 cells = 3136 chunks of 128 (round-6 config, best known).
// Round-9 change: staging via __builtin_amdgcn_global_load_lds width=16
// (direct global->LDS DMA, no VGPR round-trip, no ds_writes). LDS layout
// is linear in lane order == exactly the DMA's wave-uniform-base +
// lane*16 requirement. Two-dispatch structure is final (rounds 4/5/7:
// every intra-kernel cross-XCD handshake costs 2-4x the dispatch bubble).

#define NBATCH  8192
#define PSTRIDE 30
#define TSTRIDE 25
#define TPB     128
#define NCHUNKS 3136       // M / TPB

__device__ __forceinline__ void gll16(const void* g, void* l) {
    __builtin_amdgcn_global_load_lds(
        (const __attribute__((address_space(1))) void*)g,
        (__attribute__((address_space(3))) void*)l,
        16, 0, 0);
}

__global__ __launch_bounds__(TPB) void yolo_partial_kernel(
    const float* __restrict__ pred,
    const float* __restrict__ tgt,
    float* __restrict__ partials)
{
    __shared__ __align__(16) float sp[TPB * PSTRIDE];   // 15360 B
    __shared__ __align__(16) float st[TPB * TSTRIDE];   // 12800 B

    const int tid  = threadIdx.x;
    const int lane = tid & 63;
    const int wid  = tid >> 6;
    const size_t c0 = (size_t)blockIdx.x * TPB;

    // ---- stage pred: 15360 B = 15 x 1024B DMA segments (2 waves) ----
    const char* gpred = (const char*)(pred + c0 * PSTRIDE);
    char* lpred = (char*)sp;
    for (int s = wid; s < 15; s += 2)
        gll16(gpred + s * 1024 + lane * 16, lpred + s * 1024 + lane * 16);

    // ---- stage target: 12800 B = 12 x 1024B DMA + 512B tail ----
    const char* gtgt = (const char*)(tgt + c0 * TSTRIDE);
    char* ltgt = (char*)st;
    for (int s = wid; s < 12; s += 2)
        gll16(gtgt + s * 1024 + lane * 16, ltgt + s * 1024 + lane * 16);
    if (tid < 32)    // float4 indices 768..800 via ordinary path
        ((float4*)st)[768 + tid] = ((const float4*)gtgt)[768 + tid];

    __syncthreads();   // single drain: vmcnt(0) covers all DMA loads

    // ---- per-cell compute from LDS ----
    const float* p = sp + tid * PSTRIDE;
    const float* t = st + tid * TSTRIDE;

    int cell = (int)((c0 + tid) % 49);
    float gy = (float)(cell / 7);
    float gx = (float)(cell % 7);
    const float invS = 1.0f / 7.0f;

    float t0 = t[0], tx = t[1], ty = t[2], tw = t[3], th = t[4];
    float objf   = (t0 == 1.0f) ? 1.0f : 0.0f;
    float noobjf = (t0 == 0.0f) ? 1.0f : 0.0f;

    float tcx = (gx + tx) * invS, tcy = (gy + ty) * invS;
    float tx1 = tcx - tw * 0.5f, ty1 = tcy - th * 0.5f;
    float tx2 = tcx + tw * 0.5f, ty2 = tcy + th * 0.5f;
    float area_t = (tx2 - tx1) * (ty2 - ty1);

    float conf[2], bx[2], by[2], bw[2], bh[2], iou[2];
    #pragma unroll
    for (int b = 0; b < 2; ++b) {
        conf[b] = p[b * 5 + 0];
        bx[b]   = p[b * 5 + 1];
        by[b]   = p[b * 5 + 2];
        bw[b]   = p[b * 5 + 3];
        bh[b]   = p[b * 5 + 4];
        float ax = fabsf(bx[b]), ay = fabsf(by[b]);
        float aw = fabsf(bw[b]), ah = fabsf(bh[b]);
        float cx = (gx + ax) * invS, cy = (gy + ay) * invS;
        float x1 = cx - aw * 0.5f, y1 = cy - ah * 0.5f;
        float x2 = cx + aw * 0.5f, y2 = cy + ah * 0.5f;
        float ltx = fmaxf(x1, tx1), lty = fmaxf(y1, ty1);
        float rbx = fminf(x2, tx2), rby = fminf(y2, ty2);
        float wx = fmaxf(rbx - ltx, 0.0f);
        float wy = fmaxf(rby - lty, 0.0f);
        float inter = wx * wy;
        float area_p = (x2 - x1) * (y2 - y1);
        iou[b] = inter / (area_p + area_t - inter);
    }

    int best = (iou[1] > iou[0]) ? 1 : 0;       // first index wins ties
    float miou = fmaxf(iou[0], iou[1]);

    float rc = conf[best];
    float rx = bx[best], ry = by[best], rw = bw[best], rh = bh[best];

    float dx = rx - tx, dy = ry - ty;
    float sw = sqrtf(fabsf(rw)) - sqrtf(fabsf(tw));
    float sh = sqrtf(fabsf(rh)) - sqrtf(fabsf(th));
    float loc = dx * dx + dy * dy + sw * sw + sh * sh;

    float oc = rc - miou;
    oc = oc * oc;

    float no = conf[0] * conf[0] + conf[1] * conf[1];

    float cls = 0.0f;
    #pragma unroll
    for (int k = 0; k < 20; ++k) {
        float d = p[10 + k] - t[5 + k];
        cls += d * d;
    }

    float part = objf * (5.0f * loc + oc + cls) + 0.5f * noobjf * no;

    // ---- block reduce (2 waves), one plain store per block ----
    #pragma unroll
    for (int off = 32; off > 0; off >>= 1)
        part += __shfl_down(part, off, 64);

    __shared__ float ws[2];
    if (lane == 0) ws[wid] = part;
    __syncthreads();
    if (tid == 0)
        partials[blockIdx.x] = ws[0] + ws[1];
}

__global__ __launch_bounds__(256) void yolo_final_kernel(
    const float* __restrict__ partials,
    float* __restrict__ out, float invN)
{
    const int tid = threadIdx.x;
    float s = 0.0f;
    #pragma unroll
    for (int k = 0; k < 13; ++k) {          // 13*256 = 3328 >= 3136
        int i = tid + k * 256;
        if (i < NCHUNKS) s += partials[i];
    }
    #pragma unroll
    for (int off = 32; off > 0; off >>= 1)
        s += __shfl_down(s, off, 64);
    __shared__ float ws[4];
    int lane = tid & 63, wid = tid >> 6;
    if (lane == 0) ws[wid] = s;
    __syncthreads();
    if (tid == 0)
        out[0] = (ws[0] + ws[1] + ws[2] + ws[3]) * invN;
}

extern "C" void kernel_launch(void* const* d_in, const int* in_sizes, int n_in,
                              void* d_out, int out_size, void* d_ws, size_t ws_size,
                              hipStream_t stream) {
    const float* pred = (const float*)d_in[0];
    const float* tgt  = (const float*)d_in[1];
    float* out = (float*)d_out;
    float* partials = (float*)d_ws;        // 3136 f32, fully overwritten

    yolo_partial_kernel<<<NCHUNKS, TPB, 0, stream>>>(pred, tgt, partials);
    yolo_final_kernel<<<1, 256, 0, stream>>>(partials, out, 1.0f / (float)NBATCH);
}